// Round 1
// 7271.619 us; speedup vs baseline: 1.1104x; 1.1104x over previous
//
#include <hip/hip_runtime.h>
#include <math.h>

typedef __bf16 bf16;
typedef __bf16 bf16x8 __attribute__((ext_vector_type(8)));
typedef __bf16 bf16x2v __attribute__((ext_vector_type(2)));
typedef float f32x4 __attribute__((ext_vector_type(4)));

#define DD     1024
#define NL     8
#define NTOK   257
#define NB     64
#define DFF    4096
#define MM     (NB*NTOK)   /* 16448 */
#define NP     288         /* padded token count for attention K-loop */
#define HD     128
#define CHUNK  128         /* bh pairs per attention chunk (4 chunks of 512) */

// ---------------------------------------------------------------- async copy
__device__ __forceinline__ void gld16(const void* g, void* l) {
  __builtin_amdgcn_global_load_lds((__attribute__((address_space(1))) void*)g,
                                   (__attribute__((address_space(3))) void*)l,
                                   16, 0, 0);
}

// stage NR x 32 bf16 tile with chunk swizzle: physical slot s holds logical
// chunk (s - row/2) & 3.  LDS row = 64 B.  HW dest = wave base + lane*16.
template<int NT, int NR>
__device__ __forceinline__ void stage_sw(const bf16* __restrict__ p, int ld,
                                         int row0, int rmax, int k0,
                                         char* lds, int t) {
  int wb = (t >> 6) << 10;                       // wave-uniform LDS base
  int cs = ((((t & 3) - (t >> 3)) & 3) << 3);    // swizzled logical chunk (elems)
  #pragma unroll
  for (int i = 0; i < (NR*4)/NT; ++i) {
    int r = row0 + i*(NT/4) + (t >> 2);
    r = r < rmax ? r : rmax;
    gld16(p + (long)r*ld + k0 + cs, lds + i*(NT*16) + wb);
  }
}

// XCD-chunked bijective work swizzle (m204): hw linear id -> work id such
// that consecutive work ids land on the same XCD; decompose y-fastest so the
// blocks sharing one A row-panel are co-resident on one XCD (A fetched once).
__device__ __forceinline__ void swz_xy(int& X, int& Y) {
  int gx = gridDim.x, gy = gridDim.y;
  int G = gx * gy;
  int orig = blockIdx.y * gx + blockIdx.x;
  int q = G >> 3, r = G & 7;
  int xcd = orig & 7, j = orig >> 3;
  int wg = (xcd < r ? xcd*(q+1) : r*(q+1) + (xcd-r)*q) + j;
  X = wg / gy; Y = wg - (wg / gy) * gy;
}

// read 4 A-frags + 4 B-frags from one LDS buffer pair and do 16 MFMAs
__device__ __forceinline__ void frag_mfma(const char* cA, const char* cB,
                                          int wr, int wc, int ro, int soff,
                                          f32x4 acc[4][4]) {
  bf16x8 af[4], bfr[4];
  #pragma unroll
  for (int i = 0; i < 4; ++i)
    af[i]  = *(const bf16x8*)(cA + (wr + i*16 + ro)*64 + soff);
  #pragma unroll
  for (int j = 0; j < 4; ++j)
    bfr[j] = *(const bf16x8*)(cB + (wc + j*16 + ro)*64 + soff);
  #pragma unroll
  for (int i = 0; i < 4; ++i)
    #pragma unroll
    for (int j = 0; j < 4; ++j)
      acc[i][j] = __builtin_amdgcn_mfma_f32_16x16x32_bf16(af[i], bfr[j], acc[i][j], 0, 0, 0);
}

// 128 x BN C tile, BK=32, double-buffered 2-phase pipeline:
//   prologue: stage tile0; vmcnt(0)+barrier
//   loop:     issue stage tile t+1 (buf^1)  ->  ds_read+MFMA tile t (buf)
//             -> one barrier (drains vmcnt AFTER compute, latency hidden)
// LDS layout: [A0][A1][B0][B1], A buf 8 KB, B buf BN*64 B.
template<int NT, int BN>
__device__ __forceinline__ void gemm_core(const bf16* __restrict__ A, int lda, int ar0, int armax,
                                          const bf16* __restrict__ Bt, int ldb, int br0, int brmax,
                                          int K, f32x4 acc[4][4], char* lds) {
  int t = threadIdx.x;
  int lane = t & 63, w = t >> 6;
  int wr = (NT == 256 ? (w >> 1) : (w >> 2)) << 6;
  int wc = (NT == 256 ? (w & 1)  : (w & 3))  << 6;
  int ro = lane & 15, q = lane >> 4;
  int soff = ((q + (ro >> 1)) & 3) << 4;         // swizzle read offset (loop-inv)
  constexpr int AB = 128*64;                     // 8 KB per A buffer
  constexpr int BB = BN*64;                      // B buffer bytes
  char* lB = lds + 2*AB;

  stage_sw<NT,128>(A,  lda, ar0, armax, 0, lds, t);
  stage_sw<NT,BN> (Bt, ldb, br0, brmax, 0, lB,  t);
  __syncthreads();                               // drains prologue vmcnt
  int cur = 0;
  for (int k0 = 32; k0 < K; k0 += 32) {
    // issue next-tile loads into the other buffer (in flight during MFMA)
    stage_sw<NT,128>(A,  lda, ar0, armax, k0, lds + (cur^1)*AB, t);
    stage_sw<NT,BN> (Bt, ldb, br0, brmax, k0, lB  + (cur^1)*BB, t);
    // compute current tile
    frag_mfma(lds + cur*AB, lB + cur*BB, wr, wc, ro, soff, acc);
    __syncthreads();                             // vmcnt(0) lands after MFMAs
    cur ^= 1;
  }
  frag_mfma(lds + cur*AB, lB + cur*BB, wr, wc, ro, soff, acc);
}

#define ACC_INIT f32x4 acc[4][4]; { f32x4 z = {0.f,0.f,0.f,0.f}; \
  for (int i=0;i<4;i++) for (int j=0;j<4;j++) acc[i][j]=z; }

#define EPILOG_IDX(NT) int te = threadIdx.x; int lane_ = te & 63; int w_ = te >> 6; \
  int r0 = ((NT==256 ? (w_>>1) : (w_>>2)) << 6) + ((lane_ >> 4) << 2); \
  int c0 = ((NT==256 ? (w_&1)  : (w_&3))  << 6) + (lane_ & 15);

// ---------------------------------------------------------------- GEMM kernels
// Fused QKV: C = xn * wqkvT^T (N=3072); routes n<1024->q, <2048->k, else vT.
__global__ void __launch_bounds__(512) k_gemm_qkv(const bf16* __restrict__ A,
    const bf16* __restrict__ Bt, bf16* __restrict__ qb, bf16* __restrict__ kb,
    bf16* __restrict__ vT) {
  __shared__ char lds[2*8192 + 2*16384];
  int X, Y; swz_xy(X, Y);
  ACC_INIT;
  gemm_core<512,256>(A, DD, X*128, MM-1, Bt, DD, Y*256, 3071, DD, acc, lds);
  EPILOG_IDX(512);
  int mb = X*128, nb = Y*256;
  #pragma unroll
  for (int i=0;i<4;i++)
    #pragma unroll
    for (int r=0;r<4;r++) {
      int m = mb + r0 + i*16 + r;
      if (m < MM) {
        unsigned bb = (unsigned)m / NTOK;
        int tok = m - (int)bb*NTOK;
        #pragma unroll
        for (int j=0;j<4;j++) {
          int n = nb + c0 + j*16;
          bf16 val = (bf16)acc[i][j][r];
          if (n < 2048) {
            (n < 1024 ? qb : kb)[(long)m*DD + (n & 1023)] = val;
          } else {
            int nv = n - 2048, h = nv >> 7, d = nv & 127;
            vT[(((long)(bb*8+h))*HD + d)*NP + tok] = val;
          }
        }
      }
    }
}

// T[m][n] += A*Bt^T + bias   (fp32 residual, N=1024)
__global__ void __launch_bounds__(512) k_gemm_resid(const bf16* __restrict__ A,
    const bf16* __restrict__ Bt, const float* __restrict__ bias,
    float* __restrict__ T, int K) {
  __shared__ char lds[2*8192 + 2*16384];
  int X, Y; swz_xy(X, Y);
  ACC_INIT;
  gemm_core<512,256>(A, K, X*128, MM-1, Bt, K, Y*256, 1023, K, acc, lds);
  EPILOG_IDX(512);
  int mb = X*128, nb = Y*256;
  #pragma unroll
  for (int i=0;i<4;i++)
    #pragma unroll
    for (int r=0;r<4;r++) {
      int m = mb + r0 + i*16 + r;
      if (m < MM) {
        #pragma unroll
        for (int j=0;j<4;j++) {
          int n = nb + c0 + j*16;
          long idx = (long)m*DD + n;
          T[idx] = T[idx] + acc[i][j][r] + bias[n];
        }
      }
    }
}

// H[m][n] = gelu(A*Bt^T + bias)  (bf16, N=4096)
__global__ void __launch_bounds__(512) k_gemm_gelu(const bf16* __restrict__ A,
    const bf16* __restrict__ Bt, const float* __restrict__ bias,
    bf16* __restrict__ Hb) {
  __shared__ char lds[2*8192 + 2*16384];
  int X, Y; swz_xy(X, Y);
  ACC_INIT;
  gemm_core<512,256>(A, DD, X*128, MM-1, Bt, DD, Y*256, 4095, DD, acc, lds);
  EPILOG_IDX(512);
  int mb = X*128, nb = Y*256;
  #pragma unroll
  for (int i=0;i<4;i++)
    #pragma unroll
    for (int r=0;r<4;r++) {
      int m = mb + r0 + i*16 + r;
      if (m < MM) {
        #pragma unroll
        for (int j=0;j<4;j++) {
          int n = nb + c0 + j*16;
          float vv = acc[i][j][r] + bias[n];
          float ge = 0.5f*vv*(1.f + erff(vv*0.70710678118654752f));
          Hb[(long)m*DFF + n] = (bf16)ge;
        }
      }
    }
}

// S = Q*K^T for one chunk of CHUNK bh.  grid (3,3,CHUNK).
__global__ void __launch_bounds__(256) k_attn_s(const bf16* __restrict__ q,
    const bf16* __restrict__ kk, bf16* __restrict__ P, int bh0) {
  __shared__ char lds[2*8192 + 2*8192];
  int l = blockIdx.z; int bh = bh0 + l; int b = bh >> 3; int h = bh & 7;
  const bf16* Ab = q  + (long)b*NTOK*DD + h*HD;
  const bf16* Bb = kk + (long)b*NTOK*DD + h*HD;
  ACC_INIT;
  gemm_core<256,128>(Ab, DD, blockIdx.x*128, NTOK-1, Bb, DD, blockIdx.y*128, NTOK-1, HD, acc, lds);
  EPILOG_IDX(256);
  bf16* Pp = P + (long)l*NP*NP;
  int mb = blockIdx.x*128, nb = blockIdx.y*128;
  #pragma unroll
  for (int i=0;i<4;i++)
    #pragma unroll
    for (int r=0;r<4;r++) {
      int m = mb + r0 + i*16 + r;
      if (m < NTOK) {
        #pragma unroll
        for (int j=0;j<4;j++) {
          int n = nb + c0 + j*16;
          if (n < NTOK) Pp[(long)m*NP + n] = (bf16)acc[i][j][r];
        }
      }
    }
}

// Y = P*V^T for one chunk.  grid (3,1,CHUNK). vT[bh][d][tok].
__global__ void __launch_bounds__(256) k_attn_pv(const bf16* __restrict__ P,
    const bf16* __restrict__ vT, bf16* __restrict__ y, int bh0) {
  __shared__ char lds[2*8192 + 2*8192];
  int l = blockIdx.z; int bh = bh0 + l; int b = bh >> 3; int h = bh & 7;
  const bf16* Ab = P  + (long)l*NP*NP;
  const bf16* Bb = vT + (long)bh*HD*NP;
  ACC_INIT;
  gemm_core<256,128>(Ab, NP, blockIdx.x*128, NP-1, Bb, NP, 0, HD-1, NP, acc, lds);
  EPILOG_IDX(256);
  int mb = blockIdx.x*128;
  #pragma unroll
  for (int i=0;i<4;i++)
    #pragma unroll
    for (int r=0;r<4;r++) {
      int m = mb + r0 + i*16 + r;
      if (m < NTOK) {
        #pragma unroll
        for (int j=0;j<4;j++) {
          int n = c0 + j*16;   // head-dim 0..127
          y[((long)b*NTOK + m)*DD + h*HD + n] = (bf16)acc[i][j][r];
        }
      }
    }
}

// ---------------------------------------------------------------- elementwise
__global__ void __launch_bounds__(256) k_ln(const float* __restrict__ T,
    const float* __restrict__ g, const float* __restrict__ be,
    bf16* __restrict__ out) {
  int row = blockIdx.x;
  const float4* x4 = (const float4*)(T + (long)row*DD);
  int t = threadIdx.x;
  float4 v = x4[t];
  float s  = v.x+v.y+v.z+v.w;
  float ss = v.x*v.x+v.y*v.y+v.z*v.z+v.w*v.w;
  #pragma unroll
  for (int o=32;o;o>>=1){ s += __shfl_down(s,o); ss += __shfl_down(ss,o); }
  __shared__ float rsum[4], rsq[4];
  int lane = t&63, w = t>>6;
  if (lane==0){ rsum[w]=s; rsq[w]=ss; }
  __syncthreads();
  float S  = rsum[0]+rsum[1]+rsum[2]+rsum[3];
  float SS = rsq[0]+rsq[1]+rsq[2]+rsq[3];
  float mean = S*(1.f/DD);
  float var  = SS*(1.f/DD) - mean*mean;
  float rs = rsqrtf(var + 1e-6f);
  float4 gg = ((const float4*)g)[t];
  float4 bb = ((const float4*)be)[t];
  bf16* o = out + (long)row*DD + t*4;
  o[0]=(bf16)((v.x-mean)*rs*gg.x+bb.x);
  o[1]=(bf16)((v.y-mean)*rs*gg.y+bb.y);
  o[2]=(bf16)((v.z-mean)*rs*gg.z+bb.z);
  o[3]=(bf16)((v.w-mean)*rs*gg.w+bb.w);
}

// softmax over valid 257 cols of one P row per wave; zero cols 257..287.
__global__ void __launch_bounds__(256) k_softmax(bf16* __restrict__ P) {
  int t = threadIdx.x, lane = t & 63, w = t >> 6;
  int row = blockIdx.x*4 + w;
  int l = row / NTOK, qq = row - l*NTOK;
  bf16* p = P + (long)l*NP*NP + (long)qq*NP;
  float v[5]; float mx = -1e30f;
  #pragma unroll
  for (int i=0;i<5;i++){
    int c = lane + i*64;
    v[i] = (c < NTOK) ? (float)p[c] : -1e30f;
    mx = fmaxf(mx, v[i]);
  }
  #pragma unroll
  for (int o=32;o;o>>=1) mx = fmaxf(mx, __shfl_xor(mx, o));
  float s = 0.f;
  #pragma unroll
  for (int i=0;i<5;i++){ v[i] = __expf(v[i]-mx); s += v[i]; }
  #pragma unroll
  for (int o=32;o;o>>=1) s += __shfl_xor(s, o);
  float inv = 1.f / s;
  #pragma unroll
  for (int i=0;i<5;i++){ int c = lane + i*64; if (c < NTOK) p[c] = (bf16)(v[i]*inv); }
  if (lane < NP-NTOK) p[NTOK+lane] = (bf16)0.f;
}

// fp32 [R x C] -> bf16 [C x R] * scale.  64x64 tiles, float2 loads,
// packed bf16x2 stores.  grid (C/64, R/64), block 256.
__global__ void __launch_bounds__(256) k_transpose64(const float* __restrict__ in,
    bf16* __restrict__ out, int R, int C, float scale) {
  __shared__ float tile[64][65];
  int c0 = blockIdx.x*64, r0 = blockIdx.y*64;
  int t = threadIdx.x;
  int tr = t >> 5, tc = (t & 31) * 2;
  #pragma unroll
  for (int i = 0; i < 8; ++i) {
    int r = r0 + tr + i*8;
    float2 v = *(const float2*)&in[(long)r*C + c0 + tc];
    tile[tr + i*8][tc] = v.x; tile[tr + i*8][tc+1] = v.y;
  }
  __syncthreads();
  #pragma unroll
  for (int i = 0; i < 8; ++i) {
    int c = c0 + tr + i*8;
    bf16x2v o;
    o.x = (bf16)(tile[tc  ][tr + i*8] * scale);
    o.y = (bf16)(tile[tc+1][tr + i*8] * scale);
    *(bf16x2v*)&out[(long)c*R + r0 + tc] = o;
  }
}

// patch embed + cls + pos  -> T fp32 [MM x DD]
__global__ void __launch_bounds__(256) k_embed(const float* __restrict__ x,
    const float* __restrict__ cw, const float* __restrict__ cb,
    const float* __restrict__ cls, const float* __restrict__ pos,
    float* __restrict__ T) {
  int blk = blockIdx.x; int b = blk / NTOK, tok = blk - b*NTOK;
  long orow = (long)(b*NTOK + tok)*DD;
  int t = threadIdx.x;
  if (tok == 0) {
    #pragma unroll
    for (int i=0;i<4;i++){ int d=t+i*256; T[orow+d] = cls[d] + pos[d]; }
    return;
  }
  __shared__ float patch[48];
  int pi = tok-1, py = pi>>4, px = pi&15;
  if (t < 48) {
    int i = t/12, j = (t/3)&3, c = t%3;
    patch[t] = x[(((long)(b*64 + py*4 + i))*64 + px*4 + j)*3 + c];
  }
  __syncthreads();
  float a[4];
  #pragma unroll
  for (int i=0;i<4;i++) a[i] = cb[t+i*256];
  for (int p=0;p<48;p++){
    float pv = patch[p];
    const float* wrow = cw + p*DD;
    #pragma unroll
    for (int i=0;i<4;i++) a[i] += pv * wrow[t+i*256];
  }
  #pragma unroll
  for (int i=0;i<4;i++){ int d=t+i*256; T[orow+d] = a[i] + pos[(long)tok*DD+d]; }
}

__global__ void __launch_bounds__(256) k_out(const float* __restrict__ T,
                                             float* __restrict__ out) {
  int b = blockIdx.x, t = threadIdx.x;
  #pragma unroll
  for (int i=0;i<4;i++){
    int d = t + i*256;
    out[(long)b*DD + d] = T[(long)b*NTOK*DD + d];
  }
}

// ---------------------------------------------------------------- host
extern "C" void kernel_launch(void* const* d_in, const int* in_sizes, int n_in,
                              void* d_out, int out_size, void* d_ws, size_t ws_size,
                              hipStream_t stream) {
  const float* x      = (const float*)d_in[0];
  const float* conv_w = (const float*)d_in[1];
  const float* conv_b = (const float*)d_in[2];
  const float* cls    = (const float*)d_in[3];
  const float* pos    = (const float*)d_in[4];
  const float* ln1_g  = (const float*)d_in[5];
  const float* ln1_b  = (const float*)d_in[6];
  const float* wq     = (const float*)d_in[7];
  const float* wk     = (const float*)d_in[8];
  const float* wv     = (const float*)d_in[9];
  const float* proj_w = (const float*)d_in[10];
  const float* proj_b = (const float*)d_in[11];
  const float* ln2_g  = (const float*)d_in[12];
  const float* ln2_b  = (const float*)d_in[13];
  const float* mlp1_w = (const float*)d_in[14];
  const float* mlp1_b = (const float*)d_in[15];
  const float* mlp2_w = (const float*)d_in[16];
  const float* mlp2_b = (const float*)d_in[17];

  // ---- workspace layout (252,575,744 B total) -----------------------------
  const size_t TBUF_OFF = 0;
  const size_t XN_OFF   = 67371008;               // MM*DD*4
  const size_t C_OFF    = XN_OFF + 33685504;      // MM*DD*2
  const size_t NEED     = C_OFF + 151519232;
  if (ws_size < NEED) return;

  char* base = (char*)d_ws;
  float* tbuf  = (float*)(base + TBUF_OFF);
  bf16*  xn    = (bf16*)(base + XN_OFF);
  char*  C     = base + C_OFF;
  bf16* wqkvT  = (bf16*)(C + 0);                   // 3 x 1024 x 1024 bf16 (6 MB)
  bf16* projT  = wqkvT;                            // reused after QKV GEMM
  bf16* qb     = (bf16*)(C + 6291456);
  bf16* kb     = (bf16*)(C + 39976960);
  bf16* vT     = (bf16*)(C + 73662464);            // 512*128*288 bf16
  bf16* Pc     = (bf16*)(C + 111411200);           // CHUNK*288*288 bf16
  bf16* m1T    = (bf16*)(C + 0);
  bf16* m2T    = (bf16*)(C + 8388608);
  bf16* hb     = (bf16*)(C + 16777216);            // MM*DFF bf16

  const float qscale = 0.08838834764831845f;       // 1/sqrt(128)

  k_embed<<<MM, 256, 0, stream>>>(x, conv_w, conv_b, cls, pos, tbuf);

  for (int i = 0; i < NL; ++i) {
    const long wo = (long)i*DD*DD;
    k_transpose64<<<dim3(16,16), 256, 0, stream>>>(wq + wo, wqkvT,             DD, DD, qscale);
    k_transpose64<<<dim3(16,16), 256, 0, stream>>>(wk + wo, wqkvT + 1024*1024, DD, DD, 1.f);
    k_transpose64<<<dim3(16,16), 256, 0, stream>>>(wv + wo, wqkvT + 2*1024*1024, DD, DD, 1.f);
    k_ln<<<MM, 256, 0, stream>>>(tbuf, ln1_g + i*DD, ln1_b + i*DD, xn);
    k_gemm_qkv<<<dim3(129,12), 512, 0, stream>>>(xn, wqkvT, qb, kb, vT);
    k_transpose64<<<dim3(16,16), 256, 0, stream>>>(proj_w + wo, projT, DD, DD, 1.f);
    for (int c = 0; c < 512/CHUNK; ++c) {
      k_attn_s <<<dim3(3,3,CHUNK), 256, 0, stream>>>(qb, kb, Pc, c*CHUNK);
      k_softmax<<<(CHUNK*NTOK)/4, 256, 0, stream>>>(Pc);
      k_attn_pv<<<dim3(3,1,CHUNK), 256, 0, stream>>>(Pc, vT, xn, c*CHUNK);
    }
    k_gemm_resid<<<dim3(129,4), 512, 0, stream>>>(xn, projT, proj_b + i*DD, tbuf, DD);
    k_ln<<<MM, 256, 0, stream>>>(tbuf, ln2_g + i*DD, ln2_b + i*DD, xn);
    k_transpose64<<<dim3(64,16), 256, 0, stream>>>(mlp1_w + (long)i*DD*DFF, m1T, DD, DFF, 1.f);
    k_transpose64<<<dim3(16,64), 256, 0, stream>>>(mlp2_w + (long)i*DFF*DD, m2T, DFF, DD, 1.f);
    k_gemm_gelu <<<dim3(129,16), 512, 0, stream>>>(xn, m1T, mlp1_b + i*DFF, hb);
    k_gemm_resid<<<dim3(129,4),  512, 0, stream>>>(hb, m2T, mlp2_b + i*DD, tbuf, DFF);
  }

  k_out<<<NB, 256, 0, stream>>>(tbuf, (float*)d_out);
}